// Round 5
// baseline (346.701 us; speedup 1.0000x reference)
//
#include <hip/hip_runtime.h>
#include <cstdint>
#include <cstddef>

#define NN 100000
#define NE 1600000
#define DD 64
#define NG 64

#define EPB 4096
#define NBLK ((NE + EPB - 1) / EPB)      // 391
#define NBUCK ((NN + 511) / 512)         // 196
#define BCAP 10240
#define NBT ((NN + 63) / 64)             // 1563 fused tiles

typedef unsigned short u16;
typedef unsigned int u32;
typedef unsigned char u8;
typedef short short8 __attribute__((ext_vector_type(8)));
typedef float f32x4 __attribute__((ext_vector_type(4)));

__device__ __forceinline__ float bf2f(u16 h) {
    u32 u = ((u32)h) << 16;
    return __builtin_bit_cast(float, u);
}
__device__ __forceinline__ u16 f2bf(float f) {
    u32 u = __builtin_bit_cast(u32, f);
    u += 0x7fffu + ((u >> 16) & 1u);
    return (u16)(u >> 16);
}

// ---------------- CSR build: bucket partition, all-coalesced writes --------
__global__ void __launch_bounds__(256) k_hist(const int* __restrict__ dst,
                                              int* __restrict__ hist) {
    __shared__ int h[NBUCK];
    for (int i = threadIdx.x; i < NBUCK; i += 256) h[i] = 0;
    __syncthreads();
    const int base = blockIdx.x * EPB;
    const int end = (base + EPB < NE) ? base + EPB : NE;
    for (int i = base + threadIdx.x; i < end; i += 256)
        atomicAdd(&h[dst[i] >> 9], 1);
    __syncthreads();
    for (int i = threadIdx.x; i < NBUCK; i += 256)
        hist[i * NBLK + blockIdx.x] = h[i];
}

__global__ void __launch_bounds__(512) k_rowscan(int* __restrict__ hist,
                                                 int* __restrict__ btot) {
    __shared__ int s[2][512];
    const int b = blockIdx.x;
    const int t = threadIdx.x;
    int v = (t < NBLK) ? hist[b * NBLK + t] : 0;
    s[0][t] = v;
    __syncthreads();
    int sel = 0;
    for (int off = 1; off < 512; off <<= 1) {
        int x = s[sel][t];
        if (t >= off) x += s[sel][t - off];
        s[sel ^ 1][t] = x;
        __syncthreads();
        sel ^= 1;
    }
    if (t < NBLK) hist[b * NBLK + t] = s[sel][t] - v;
    if (t == 511) btot[b] = s[sel][511];
}

__global__ void __launch_bounds__(256) k_btscan(int* __restrict__ btot) {
    __shared__ int s[2][256];
    const int t = threadIdx.x;
    int v = (t < NBUCK) ? btot[t] : 0;
    s[0][t] = v;
    __syncthreads();
    int sel = 0;
    for (int off = 1; off < 256; off <<= 1) {
        int x = s[sel][t];
        if (t >= off) x += s[sel][t - off];
        s[sel ^ 1][t] = x;
        __syncthreads();
        sel ^= 1;
    }
    if (t < NBUCK) btot[t] = s[sel][t] - v;
    if (t == 0) btot[NBUCK] = NE;
}

__global__ void __launch_bounds__(256) k_part(const int* __restrict__ src,
                                              const int* __restrict__ dst,
                                              const int* __restrict__ excl,
                                              const int* __restrict__ btot,
                                              u32* __restrict__ part) {
    __shared__ int cnt[NBUCK];
    __shared__ int diff[NBUCK];
    __shared__ int cur[NBUCK];
    __shared__ int sc[2][256];
    __shared__ u32 pk[EPB];
    __shared__ u8  bk[EPB];
    const int t = threadIdx.x;
    const int blk = blockIdx.x;
    const int base = blk * EPB;
    const int n = ((base + EPB < NE) ? EPB : NE - base);
    for (int i = t; i < NBUCK; i += 256) cnt[i] = 0;
    __syncthreads();

    int myb[EPB / 256];
    u32 mypk[EPB / 256];
#pragma unroll
    for (int j = 0; j < EPB / 256; ++j) {
        int i = t + j * 256;
        bool ok = i < n;
        int d = ok ? dst[base + i] : 0;
        int s2 = ok ? src[base + i] : 0;
        int b = d >> 9;
        myb[j] = b;
        mypk[j] = ((u32)(d & 511) << 17) | (u32)s2;
        if (ok) atomicAdd(&cnt[b], 1);
    }
    __syncthreads();
    int v = (t < NBUCK) ? cnt[t] : 0;
    sc[0][t] = v;
    __syncthreads();
    int sel = 0;
    for (int off = 1; off < 256; off <<= 1) {
        int x = sc[sel][t];
        if (t >= off) x += sc[sel][t - off];
        sc[sel ^ 1][t] = x;
        __syncthreads();
        sel ^= 1;
    }
    if (t < NBUCK) {
        int e = sc[sel][t] - v;
        cur[t] = e;
        diff[t] = excl[t * NBLK + blk] + btot[t] - e;
    }
    __syncthreads();
#pragma unroll
    for (int j = 0; j < EPB / 256; ++j) {
        int i = t + j * 256;
        if (i < n) {
            int pos = atomicAdd(&cur[myb[j]], 1);
            pk[pos] = mypk[j];
            bk[pos] = (u8)myb[j];
        }
    }
    __syncthreads();
    for (int p = t; p < n; p += 256)
        part[diff[bk[p]] + p] = pk[p];
}

__global__ void __launch_bounds__(512) k_bucket(const u32* __restrict__ part,
                                                const int* __restrict__ btot,
                                                int* __restrict__ row_off,
                                                int* __restrict__ srcs,
                                                float* __restrict__ deg_inv) {
    __shared__ int cnt[512];
    __shared__ int cur[512];
    __shared__ int sc[2][512];
    __shared__ int lsrc[BCAP];
    const int b = blockIdx.x;
    const int t = threadIdx.x;
    const int base = btot[b];
    const int endp = btot[b + 1];
    const int n = endp - base;
    cnt[t] = 0;
    __syncthreads();
    for (int i = t; i < n; i += 512)
        atomicAdd(&cnt[part[base + i] >> 17], 1);
    __syncthreads();
    int v = cnt[t];
    sc[0][t] = v;
    __syncthreads();
    int sel = 0;
    for (int off = 1; off < 512; off <<= 1) {
        int x = sc[sel][t];
        if (t >= off) x += sc[sel][t - off];
        sc[sel ^ 1][t] = x;
        __syncthreads();
        sel ^= 1;
    }
    const int el = sc[sel][t] - v;
    const int g = b * 512 + t;
    if (g < NN) {
        row_off[g] = base + el;
        deg_inv[g] = (v > 0) ? 1.0f / (float)v : 0.0f;
    }
    if (b == NBUCK - 1 && t == 0) row_off[NN] = NE;
    cur[t] = el;
    __syncthreads();
    for (int i = t; i < n; i += 512) {
        u32 p = part[base + i];
        int pos = atomicAdd(&cur[p >> 17], 1);
        int s2 = (int)(p & 0x1FFFFu);
        if (pos < BCAP) lsrc[pos] = s2;
        else srcs[base + pos] = s2;
    }
    __syncthreads();
    const int lim = (n < BCAP) ? n : BCAP;
    for (int i = t; i < lim; i += 512)
        srcs[base + i] = lsrc[i];
}

// ---------------- fp32 -> bf16 ----------------
__global__ void k_cvt(const float* __restrict__ x, u16* __restrict__ xb) {
    int i = blockIdx.x * blockDim.x + threadIdx.x;
    int stride = gridDim.x * blockDim.x;
    const int total = NN * DD / 4;
    for (; i < total; i += stride) {
        float4 v = ((const float4*)x)[i];
        u32 p0 = (u32)f2bf(v.x) | ((u32)f2bf(v.y) << 16);
        u32 p1 = (u32)f2bf(v.z) | ((u32)f2bf(v.w) << 16);
        uint2 pk; pk.x = p0; pk.y = p1;
        ((uint2*)xb)[i] = pk;
    }
}

// ---------------- fused layer: gather (mean) + dual GEMM + bias (+relu) ----
// Block = 4 waves = 64 nodes. Wave w gathers nodes [n0w, n0w+16) into an
// XOR-swizzled LDS tile, then MFMAs its own 16-node tile with LDS-staged
// bf16 weights. agg never touches global memory.
__global__ void __launch_bounds__(256) k_fused(
    const u16* __restrict__ hin, u16* __restrict__ hout,
    const float* __restrict__ Wl, const float* __restrict__ bl,
    const float* __restrict__ Wr,
    const int* __restrict__ row_off, const int* __restrict__ srcs,
    const float* __restrict__ deg_inv, int relu) {
    __shared__ int ids[4][64];
    __shared__ __align__(16) u8 aggT[4][2048];   // 16 rows x 128B, swizzled
    __shared__ __align__(16) u8 Wlds[2][8192];   // bf16 weights, swizzled
    const int tid  = threadIdx.x;
    const int lane = tid & 63;
    const int wid  = tid >> 6;
    const int half = lane >> 5;
    const int fp   = (lane & 31) * 2;
    const int n0w  = blockIdx.x * 64 + wid * 16;

    // stage both weight matrices to LDS (bf16, row-swizzled)
#pragma unroll
    for (int m = 0; m < 2; ++m) {
        const float* W = m ? Wr : Wl;
        for (int idx = tid; idx < 64 * 32; idx += 256) {
            int row = idx >> 5;
            int cb = (idx & 31) * 4;
            float2 v2 = *(const float2*)&W[row * 64 + (idx & 31) * 2];
            u32 pk = (u32)f2bf(v2.x) | ((u32)f2bf(v2.y) << 16);
            *(u32*)&Wlds[m][row * 128 + (cb ^ ((row & 7) << 4))] = pk;
        }
    }

    // ---- gather phase: 16 nodes per wave ----
    int n = n0w;
    int beg = 0, end = 0;
    if (n < NN) { beg = row_off[n]; end = row_off[n + 1]; }
    int myid = (beg + lane < end) ? srcs[beg + lane] : 0;

#define PAIR(J, SLO, SHI) { \
        int _id = ids[wid][(J) + half]; \
        u32 _v = *(const u32*)&hin[(size_t)_id * DD + fp]; \
        SLO += __builtin_bit_cast(float, _v << 16); \
        SHI += __builtin_bit_cast(float, _v & 0xffff0000u); }

    for (int j = 0; j < 16; ++j) {
        ids[wid][lane] = myid;
        __builtin_amdgcn_wave_barrier();
        // prefetch next node's ids
        int n2 = n0w + j + 1;
        int beg2 = 0, end2 = 0;
        if (j < 15 && n2 < NN) { beg2 = row_off[n2]; end2 = row_off[n2 + 1]; }
        myid = (beg2 + lane < end2) ? srcs[beg2 + lane] : 0;
        const float dinv = (n0w + j < NN) ? deg_inv[n0w + j] : 0.f;

        int deg = end - beg;
        int cnt = deg < 64 ? deg : 64;
        float s0 = 0.f, s1 = 0.f, t0 = 0.f, t1 = 0.f;
        float u0 = 0.f, u1 = 0.f, w0 = 0.f, w1 = 0.f;
        int jq = 0;
        for (; jq + 16 <= cnt; jq += 16) {
            PAIR(jq + 0,  s0, s1)
            PAIR(jq + 2,  t0, t1)
            PAIR(jq + 4,  u0, u1)
            PAIR(jq + 6,  w0, w1)
            PAIR(jq + 8,  s0, s1)
            PAIR(jq + 10, t0, t1)
            PAIR(jq + 12, u0, u1)
            PAIR(jq + 14, w0, w1)
        }
        for (; jq + 2 <= cnt; jq += 2) PAIR(jq, s0, s1)
        if (jq < cnt) {
            int _id = ids[wid][jq];
            if (half == 0) {
                u32 _v = *(const u32*)&hin[(size_t)_id * DD + fp];
                s0 += __builtin_bit_cast(float, _v << 16);
                s1 += __builtin_bit_cast(float, _v & 0xffff0000u);
            }
        }
        for (int base2 = 64; base2 < deg; base2 += 64) {   // rare deg>64
            __builtin_amdgcn_wave_barrier();
            int m = deg - base2; if (m > 64) m = 64;
            if (lane < m) ids[wid][lane] = srcs[beg + base2 + lane];
            __builtin_amdgcn_wave_barrier();
            int j2 = 0;
            for (; j2 + 2 <= m; j2 += 2) PAIR(j2, s0, s1)
            if (j2 < m) {
                int _id = ids[wid][j2];
                if (half == 0) {
                    u32 _v = *(const u32*)&hin[(size_t)_id * DD + fp];
                    s0 += __builtin_bit_cast(float, _v << 16);
                    s1 += __builtin_bit_cast(float, _v & 0xffff0000u);
                }
            }
        }
        float aLo = (s0 + t0) + (u0 + w0);
        float aHi = (s1 + t1) + (u1 + w1);
        aLo += __shfl_xor(aLo, 32);
        aHi += __shfl_xor(aHi, 32);
        aLo *= dinv; aHi *= dinv;
        if (half == 0) {
            u32 pk = (u32)f2bf(aLo) | ((u32)f2bf(aHi) << 16);
            *(u32*)&aggT[wid][j * 128 + ((fp * 2) ^ ((j & 7) << 4))] = pk;
        }
        beg = beg2; end = end2;
        __builtin_amdgcn_wave_barrier();
    }
#undef PAIR

    __syncthreads();   // weights staged + (own-wave) agg tile complete

    // ---- MFMA phase: wave's own 16-node tile ----
    if (n0w < NN) {
        const int r = lane & 15, g = lane >> 4;
        f32x4 acc[4] = {};
#pragma unroll
        for (int kc = 0; kc < 2; ++kc) {
            const int cb = kc * 64 + g * 16;
            short8 aA = *(const short8*)&aggT[wid][r * 128 + (cb ^ ((r & 7) << 4))];
            int hrow = n0w + r; if (hrow > NN - 1) hrow = NN - 1;
            short8 aH = *(const short8*)&hin[(size_t)hrow * DD + kc * 32 + g * 8];
#pragma unroll
            for (int ct = 0; ct < 4; ++ct) {
                const int wb = (ct * 16 + r) * 128 + (cb ^ ((r & 7) << 4));
                short8 bA = *(const short8*)&Wlds[0][wb];
                short8 bH = *(const short8*)&Wlds[1][wb];
                acc[ct] = __builtin_amdgcn_mfma_f32_16x16x32_bf16(aA, bA, acc[ct], 0, 0, 0);
                acc[ct] = __builtin_amdgcn_mfma_f32_16x16x32_bf16(aH, bH, acc[ct], 0, 0, 0);
            }
        }
#pragma unroll
        for (int ct = 0; ct < 4; ++ct) {
            float bias = bl[ct * 16 + r];
#pragma unroll
            for (int e = 0; e < 4; ++e) {
                int node = n0w + g * 4 + e;
                if (node < NN) {
                    float v = acc[ct][e] + bias;
                    if (relu) v = fmaxf(v, 0.f);
                    hout[(size_t)node * DD + ct * 16 + r] = f2bf(v);
                }
            }
        }
    }
}

// ---------------- graph readout ----------------
__global__ void k_reduce(const u16* __restrict__ h, const int* __restrict__ batch,
                         float* __restrict__ out) {
    const int lane = threadIdx.x & 63;
    const int wid  = threadIdx.x >> 6;
    const int gw   = blockIdx.x * 4 + wid;
    const int start = gw * 64;
    if (start >= NN) return;
    const int endn = (start + 64 < NN) ? start + 64 : NN;
    float acc = 0.f;
    int gcur = batch[start];
    for (int i = start; i < endn; ++i) {
        int g = batch[i];
        if (g != gcur) {
            atomicAdd(&out[gcur * DD + lane], acc);
            acc = 0.f;
            gcur = g;
        }
        acc += bf2f(h[(size_t)i * DD + lane]);
    }
    atomicAdd(&out[gcur * DD + lane], acc);
}

extern "C" void kernel_launch(void* const* d_in, const int* in_sizes, int n_in,
                              void* d_out, int out_size, void* d_ws, size_t ws_size,
                              hipStream_t stream) {
    const float* x     = (const float*)d_in[0];
    const int*   ei    = (const int*)d_in[1];
    const int*   batch = (const int*)d_in[2];
    const float* Wl[3] = {(const float*)d_in[3], (const float*)d_in[6], (const float*)d_in[9]};
    const float* bl[3] = {(const float*)d_in[4], (const float*)d_in[7], (const float*)d_in[10]};
    const float* Wr[3] = {(const float*)d_in[5], (const float*)d_in[8], (const float*)d_in[11]};
    float* out = (float*)d_out;

    char* ws = (char*)d_ws;
    size_t off = 0;
    auto alloc = [&](size_t bytes) -> void* {
        void* p = ws + off;
        off = (off + bytes + 255) & ~(size_t)255;
        return p;
    };
    int*   hist    = (int*)  alloc((size_t)NBUCK * NBLK * 4);
    int*   btot    = (int*)  alloc(((size_t)NBUCK + 1) * 4);
    float* deg_inv = (float*)alloc((size_t)NN * 4);
    int*   row_off = (int*)  alloc(((size_t)NN + 1) * 4);
    int*   srcs    = (int*)  alloc((size_t)NE * 4);
    u32*   part    = (u32*)  alloc((size_t)NE * 4);
    u16*   xb      = (u16*)  alloc((size_t)NN * DD * 2);
    u16*   hAb     = (u16*)  alloc((size_t)NN * DD * 2);
    u16*   hBb     = (u16*)  alloc((size_t)NN * DD * 2);

    const int* e_src = ei;       // edge_index[0]
    const int* e_dst = ei + NE;  // edge_index[1]

    hipMemsetAsync(out, 0, (size_t)NG * DD * 4, stream);

    k_hist<<<NBLK, 256, 0, stream>>>(e_dst, hist);
    k_rowscan<<<NBUCK, 512, 0, stream>>>(hist, btot);
    k_btscan<<<1, 256, 0, stream>>>(btot);
    k_part<<<NBLK, 256, 0, stream>>>(e_src, e_dst, hist, btot, part);
    k_bucket<<<NBUCK, 512, 0, stream>>>(part, btot, row_off, srcs, deg_inv);
    k_cvt<<<2048, 256, 0, stream>>>(x, xb);

    k_fused<<<NBT, 256, 0, stream>>>(xb,  hAb, Wl[0], bl[0], Wr[0], row_off, srcs, deg_inv, 1);
    k_fused<<<NBT, 256, 0, stream>>>(hAb, hBb, Wl[1], bl[1], Wr[1], row_off, srcs, deg_inv, 1);
    k_fused<<<NBT, 256, 0, stream>>>(hBb, hAb, Wl[2], bl[2], Wr[2], row_off, srcs, deg_inv, 0);

    k_reduce<<<(NN / 64 + 4) / 4, 256, 0, stream>>>(hAb, batch, out);
}

// Round 6
// 240.552 us; speedup vs baseline: 1.4413x; 1.4413x over previous
//
#include <hip/hip_runtime.h>
#include <cstdint>
#include <cstddef>

#define NN 100000
#define NE 1600000
#define DD 64
#define NG 64

#define EPB 4096
#define NBLK ((NE + EPB - 1) / EPB)      // 391
#define NBUCK ((NN + 511) / 512)         // 196
#define BCAP 10240
#define NTILE (NN / 16)                  // 6250 (NN % 16 == 0)
#define NBT ((NTILE + 3) / 4)            // 1563 blocks

typedef unsigned short u16;
typedef unsigned int u32;
typedef unsigned char u8;
typedef short short8 __attribute__((ext_vector_type(8)));
typedef float f32x4 __attribute__((ext_vector_type(4)));

__device__ __forceinline__ float bf2f(u16 h) {
    u32 u = ((u32)h) << 16;
    return __builtin_bit_cast(float, u);
}
__device__ __forceinline__ u16 f2bf(float f) {
    u32 u = __builtin_bit_cast(u32, f);
    u += 0x7fffu + ((u >> 16) & 1u);
    return (u16)(u >> 16);
}

// ---------------- CSR build: bucket partition, all-coalesced writes --------
__global__ void __launch_bounds__(256) k_hist(const int* __restrict__ dst,
                                              int* __restrict__ hist) {
    __shared__ int h[NBUCK];
    for (int i = threadIdx.x; i < NBUCK; i += 256) h[i] = 0;
    __syncthreads();
    const int base = blockIdx.x * EPB;
    const int end = (base + EPB < NE) ? base + EPB : NE;
    for (int i = base + threadIdx.x; i < end; i += 256)
        atomicAdd(&h[dst[i] >> 9], 1);
    __syncthreads();
    for (int i = threadIdx.x; i < NBUCK; i += 256)
        hist[i * NBLK + blockIdx.x] = h[i];
}

__global__ void __launch_bounds__(512) k_rowscan(int* __restrict__ hist,
                                                 int* __restrict__ btot) {
    __shared__ int s[2][512];
    const int b = blockIdx.x;
    const int t = threadIdx.x;
    int v = (t < NBLK) ? hist[b * NBLK + t] : 0;
    s[0][t] = v;
    __syncthreads();
    int sel = 0;
    for (int off = 1; off < 512; off <<= 1) {
        int x = s[sel][t];
        if (t >= off) x += s[sel][t - off];
        s[sel ^ 1][t] = x;
        __syncthreads();
        sel ^= 1;
    }
    if (t < NBLK) hist[b * NBLK + t] = s[sel][t] - v;
    if (t == 511) btot[b] = s[sel][511];
}

__global__ void __launch_bounds__(256) k_btscan(int* __restrict__ btot) {
    __shared__ int s[2][256];
    const int t = threadIdx.x;
    int v = (t < NBUCK) ? btot[t] : 0;
    s[0][t] = v;
    __syncthreads();
    int sel = 0;
    for (int off = 1; off < 256; off <<= 1) {
        int x = s[sel][t];
        if (t >= off) x += s[sel][t - off];
        s[sel ^ 1][t] = x;
        __syncthreads();
        sel ^= 1;
    }
    if (t < NBUCK) btot[t] = s[sel][t] - v;
    if (t == 0) btot[NBUCK] = NE;
}

__global__ void __launch_bounds__(256) k_part(const int* __restrict__ src,
                                              const int* __restrict__ dst,
                                              const int* __restrict__ excl,
                                              const int* __restrict__ btot,
                                              u32* __restrict__ part) {
    __shared__ int cnt[NBUCK];
    __shared__ int diff[NBUCK];
    __shared__ int cur[NBUCK];
    __shared__ int sc[2][256];
    __shared__ u32 pk[EPB];
    __shared__ u8  bk[EPB];
    const int t = threadIdx.x;
    const int blk = blockIdx.x;
    const int base = blk * EPB;
    const int n = ((base + EPB < NE) ? EPB : NE - base);
    for (int i = t; i < NBUCK; i += 256) cnt[i] = 0;
    __syncthreads();

    int myb[EPB / 256];
    u32 mypk[EPB / 256];
#pragma unroll
    for (int j = 0; j < EPB / 256; ++j) {
        int i = t + j * 256;
        bool ok = i < n;
        int d = ok ? dst[base + i] : 0;
        int s2 = ok ? src[base + i] : 0;
        int b = d >> 9;
        myb[j] = b;
        mypk[j] = ((u32)(d & 511) << 17) | (u32)s2;
        if (ok) atomicAdd(&cnt[b], 1);
    }
    __syncthreads();
    int v = (t < NBUCK) ? cnt[t] : 0;
    sc[0][t] = v;
    __syncthreads();
    int sel = 0;
    for (int off = 1; off < 256; off <<= 1) {
        int x = sc[sel][t];
        if (t >= off) x += sc[sel][t - off];
        sc[sel ^ 1][t] = x;
        __syncthreads();
        sel ^= 1;
    }
    if (t < NBUCK) {
        int e = sc[sel][t] - v;
        cur[t] = e;
        diff[t] = excl[t * NBLK + blk] + btot[t] - e;
    }
    __syncthreads();
#pragma unroll
    for (int j = 0; j < EPB / 256; ++j) {
        int i = t + j * 256;
        if (i < n) {
            int pos = atomicAdd(&cur[myb[j]], 1);
            pk[pos] = mypk[j];
            bk[pos] = (u8)myb[j];
        }
    }
    __syncthreads();
    for (int p = t; p < n; p += 256)
        part[diff[bk[p]] + p] = pk[p];
}

__global__ void __launch_bounds__(512) k_bucket(const u32* __restrict__ part,
                                                const int* __restrict__ btot,
                                                int* __restrict__ row_off,
                                                int* __restrict__ srcs,
                                                float* __restrict__ deg_inv) {
    __shared__ int cnt[512];
    __shared__ int cur[512];
    __shared__ int sc[2][512];
    __shared__ int lsrc[BCAP];
    const int b = blockIdx.x;
    const int t = threadIdx.x;
    const int base = btot[b];
    const int endp = btot[b + 1];
    const int n = endp - base;
    cnt[t] = 0;
    __syncthreads();
    for (int i = t; i < n; i += 512)
        atomicAdd(&cnt[part[base + i] >> 17], 1);
    __syncthreads();
    int v = cnt[t];
    sc[0][t] = v;
    __syncthreads();
    int sel = 0;
    for (int off = 1; off < 512; off <<= 1) {
        int x = sc[sel][t];
        if (t >= off) x += sc[sel][t - off];
        sc[sel ^ 1][t] = x;
        __syncthreads();
        sel ^= 1;
    }
    const int el = sc[sel][t] - v;
    const int g = b * 512 + t;
    if (g < NN) {
        row_off[g] = base + el;
        deg_inv[g] = (v > 0) ? 1.0f / (float)v : 0.0f;
    }
    if (b == NBUCK - 1 && t == 0) row_off[NN] = NE;
    cur[t] = el;
    __syncthreads();
    for (int i = t; i < n; i += 512) {
        u32 p = part[base + i];
        int pos = atomicAdd(&cur[p >> 17], 1);
        int s2 = (int)(p & 0x1FFFFu);
        if (pos < BCAP) lsrc[pos] = s2;
        else srcs[base + pos] = s2;
    }
    __syncthreads();
    const int lim = (n < BCAP) ? n : BCAP;
    for (int i = t; i < lim; i += 512)
        srcs[base + i] = lsrc[i];
}

// ---------------- fp32 -> bf16 (features) ----------------
__global__ void k_cvt(const float* __restrict__ x, u16* __restrict__ xb) {
    int i = blockIdx.x * blockDim.x + threadIdx.x;
    int stride = gridDim.x * blockDim.x;
    const int total = NN * DD / 4;
    for (; i < total; i += stride) {
        float4 v = ((const float4*)x)[i];
        u32 p0 = (u32)f2bf(v.x) | ((u32)f2bf(v.y) << 16);
        u32 p1 = (u32)f2bf(v.z) | ((u32)f2bf(v.w) << 16);
        uint2 pk; pk.x = p0; pk.y = p1;
        ((uint2*)xb)[i] = pk;
    }
}

// ---------------- fp32 -> bf16 (all 6 weight matrices, one launch) --------
// wb layout: [layer][{Wl,Wr}][64*64]
__global__ void __launch_bounds__(256) k_cvtw6(
    const float* __restrict__ w0, const float* __restrict__ w1,
    const float* __restrict__ w2, const float* __restrict__ w3,
    const float* __restrict__ w4, const float* __restrict__ w5,
    u16* __restrict__ wb) {
    const float* ws[6] = {w0, w1, w2, w3, w4, w5};
    int i = blockIdx.x * 256 + threadIdx.x;   // grid 96 -> 24576 = 6*4096
    wb[i] = f2bf(ws[i >> 12][i & 4095]);
}

// ---------------- fused layer: gather (mean) + dual GEMM + bias (+relu) ----
// One INDEPENDENT wave per 16-node tile; no __syncthreads. Per-wave LDS:
// ids (256B) + swizzled agg tile (2KB). Weights read from global bf16 (L1-
// resident) after the gather, behind a fence so they don't inflate gather
// register pressure.
__global__ void __launch_bounds__(256) k_fused(
    const u16* __restrict__ hin, u16* __restrict__ hout,
    const u16* __restrict__ wb,   // [2][4096] bf16: Wl, Wr
    const float* __restrict__ bl,
    const int* __restrict__ row_off, const int* __restrict__ srcs,
    const float* __restrict__ deg_inv, int relu) {
    __shared__ int ids[4][64];
    __shared__ __align__(16) u8 aggT[4][2048];   // 16 rows x 128B, swizzled
    const int tid  = threadIdx.x;
    const int lane = tid & 63;
    const int wid  = tid >> 6;
    const int half = lane >> 5;
    const int fp   = (lane & 31) * 2;
    const int tile = blockIdx.x * 4 + wid;
    if (tile >= NTILE) return;
    const int n0 = tile * 16;

    // ---- gather phase: 16 nodes, wave-private ----
    int beg = row_off[n0], end = row_off[n0 + 1];
    int myid = (beg + lane < end) ? srcs[beg + lane] : 0;

#define PAIR(J, SLO, SHI) { \
        int _id = ids[wid][(J) + half]; \
        u32 _v = *(const u32*)&hin[(size_t)_id * DD + fp]; \
        SLO += __builtin_bit_cast(float, _v << 16); \
        SHI += __builtin_bit_cast(float, _v & 0xffff0000u); }

    for (int j = 0; j < 16; ++j) {
        ids[wid][lane] = myid;
        __builtin_amdgcn_wave_barrier();
        // prefetch next node's ids
        int beg2 = 0, end2 = 0;
        if (j < 15) { beg2 = row_off[n0 + j + 1]; end2 = row_off[n0 + j + 2]; }
        myid = (beg2 + lane < end2) ? srcs[beg2 + lane] : 0;
        const float dinv = deg_inv[n0 + j];

        int deg = end - beg;
        int cnt = deg < 64 ? deg : 64;
        float s0 = 0.f, s1 = 0.f, t0 = 0.f, t1 = 0.f;
        float u0 = 0.f, u1 = 0.f, w0 = 0.f, w1 = 0.f;
        int jq = 0;
        for (; jq + 16 <= cnt; jq += 16) {
            PAIR(jq + 0,  s0, s1)
            PAIR(jq + 2,  t0, t1)
            PAIR(jq + 4,  u0, u1)
            PAIR(jq + 6,  w0, w1)
            PAIR(jq + 8,  s0, s1)
            PAIR(jq + 10, t0, t1)
            PAIR(jq + 12, u0, u1)
            PAIR(jq + 14, w0, w1)
        }
        for (; jq + 2 <= cnt; jq += 2) PAIR(jq, s0, s1)
        if (jq < cnt) {
            int _id = ids[wid][jq];
            if (half == 0) {
                u32 _v = *(const u32*)&hin[(size_t)_id * DD + fp];
                s0 += __builtin_bit_cast(float, _v << 16);
                s1 += __builtin_bit_cast(float, _v & 0xffff0000u);
            }
        }
        for (int base2 = 64; base2 < deg; base2 += 64) {   // rare deg>64
            __builtin_amdgcn_wave_barrier();
            int m = deg - base2; if (m > 64) m = 64;
            if (lane < m) ids[wid][lane] = srcs[beg + base2 + lane];
            __builtin_amdgcn_wave_barrier();
            int j2 = 0;
            for (; j2 + 2 <= m; j2 += 2) PAIR(j2, s0, s1)
            if (j2 < m) {
                int _id = ids[wid][j2];
                if (half == 0) {
                    u32 _v = *(const u32*)&hin[(size_t)_id * DD + fp];
                    s0 += __builtin_bit_cast(float, _v << 16);
                    s1 += __builtin_bit_cast(float, _v & 0xffff0000u);
                }
            }
        }
        float aLo = (s0 + t0) + (u0 + w0);
        float aHi = (s1 + t1) + (u1 + w1);
        aLo += __shfl_xor(aLo, 32);
        aHi += __shfl_xor(aHi, 32);
        aLo *= dinv; aHi *= dinv;
        if (half == 0) {
            u32 pk = (u32)f2bf(aLo) | ((u32)f2bf(aHi) << 16);
            *(u32*)&aggT[wid][j * 128 + ((fp * 2) ^ ((j & 7) << 4))] = pk;
        }
        beg = beg2; end = end2;
        __builtin_amdgcn_wave_barrier();
    }
#undef PAIR

    asm volatile("" ::: "memory");   // keep weight loads out of gather phase

    // ---- MFMA phase: wave's own 16-node tile ----
    const int r = lane & 15, g = lane >> 4;
    f32x4 acc[4] = {};
#pragma unroll
    for (int kc = 0; kc < 2; ++kc) {
        const int cb = kc * 64 + g * 16;
        short8 aA = *(const short8*)&aggT[wid][r * 128 + (cb ^ ((r & 7) << 4))];
        short8 aH = *(const short8*)&hin[(size_t)(n0 + r) * DD + kc * 32 + g * 8];
#pragma unroll
        for (int ct = 0; ct < 4; ++ct) {
            const int wrow = (ct * 16 + r) * DD + kc * 32 + g * 8;
            short8 bA = *(const short8*)&wb[wrow];
            short8 bH = *(const short8*)&wb[4096 + wrow];
            acc[ct] = __builtin_amdgcn_mfma_f32_16x16x32_bf16(aA, bA, acc[ct], 0, 0, 0);
            acc[ct] = __builtin_amdgcn_mfma_f32_16x16x32_bf16(aH, bH, acc[ct], 0, 0, 0);
        }
    }
#pragma unroll
    for (int ct = 0; ct < 4; ++ct) {
        float bias = bl[ct * 16 + r];
#pragma unroll
        for (int e = 0; e < 4; ++e) {
            float v = acc[ct][e] + bias;
            if (relu) v = fmaxf(v, 0.f);
            hout[(size_t)(n0 + g * 4 + e) * DD + ct * 16 + r] = f2bf(v);
        }
    }
}

// ---------------- graph readout ----------------
__global__ void k_reduce(const u16* __restrict__ h, const int* __restrict__ batch,
                         float* __restrict__ out) {
    const int lane = threadIdx.x & 63;
    const int wid  = threadIdx.x >> 6;
    const int gw   = blockIdx.x * 4 + wid;
    const int start = gw * 64;
    if (start >= NN) return;
    const int endn = (start + 64 < NN) ? start + 64 : NN;
    float acc = 0.f;
    int gcur = batch[start];
    for (int i = start; i < endn; ++i) {
        int g = batch[i];
        if (g != gcur) {
            atomicAdd(&out[gcur * DD + lane], acc);
            acc = 0.f;
            gcur = g;
        }
        acc += bf2f(h[(size_t)i * DD + lane]);
    }
    atomicAdd(&out[gcur * DD + lane], acc);
}

extern "C" void kernel_launch(void* const* d_in, const int* in_sizes, int n_in,
                              void* d_out, int out_size, void* d_ws, size_t ws_size,
                              hipStream_t stream) {
    const float* x     = (const float*)d_in[0];
    const int*   ei    = (const int*)d_in[1];
    const int*   batch = (const int*)d_in[2];
    const float* Wl[3] = {(const float*)d_in[3], (const float*)d_in[6], (const float*)d_in[9]};
    const float* bl[3] = {(const float*)d_in[4], (const float*)d_in[7], (const float*)d_in[10]};
    const float* Wr[3] = {(const float*)d_in[5], (const float*)d_in[8], (const float*)d_in[11]};
    float* out = (float*)d_out;

    char* ws = (char*)d_ws;
    size_t off = 0;
    auto alloc = [&](size_t bytes) -> void* {
        void* p = ws + off;
        off = (off + bytes + 255) & ~(size_t)255;
        return p;
    };
    int*   hist    = (int*)  alloc((size_t)NBUCK * NBLK * 4);
    int*   btot    = (int*)  alloc(((size_t)NBUCK + 1) * 4);
    float* deg_inv = (float*)alloc((size_t)NN * 4);
    int*   row_off = (int*)  alloc(((size_t)NN + 1) * 4);
    int*   srcs    = (int*)  alloc((size_t)NE * 4);
    u32*   part    = (u32*)  alloc((size_t)NE * 4);
    u16*   wbuf    = (u16*)  alloc((size_t)6 * 4096 * 2);
    u16*   xb      = (u16*)  alloc((size_t)NN * DD * 2);
    u16*   hAb     = (u16*)  alloc((size_t)NN * DD * 2);
    u16*   hBb     = (u16*)  alloc((size_t)NN * DD * 2);

    const int* e_src = ei;       // edge_index[0]
    const int* e_dst = ei + NE;  // edge_index[1]

    hipMemsetAsync(out, 0, (size_t)NG * DD * 4, stream);

    k_hist<<<NBLK, 256, 0, stream>>>(e_dst, hist);
    k_rowscan<<<NBUCK, 512, 0, stream>>>(hist, btot);
    k_btscan<<<1, 256, 0, stream>>>(btot);
    k_part<<<NBLK, 256, 0, stream>>>(e_src, e_dst, hist, btot, part);
    k_bucket<<<NBUCK, 512, 0, stream>>>(part, btot, row_off, srcs, deg_inv);
    k_cvt<<<2048, 256, 0, stream>>>(x, xb);
    k_cvtw6<<<96, 256, 0, stream>>>(Wl[0], Wr[0], Wl[1], Wr[1], Wl[2], Wr[2], wbuf);

    k_fused<<<NBT, 256, 0, stream>>>(xb,  hAb, wbuf,            bl[0], row_off, srcs, deg_inv, 1);
    k_fused<<<NBT, 256, 0, stream>>>(hAb, hBb, wbuf + 1 * 8192, bl[1], row_off, srcs, deg_inv, 1);
    k_fused<<<NBT, 256, 0, stream>>>(hBb, hAb, wbuf + 2 * 8192, bl[2], row_off, srcs, deg_inv, 0);

    k_reduce<<<(NN / 64 + 4) / 4, 256, 0, stream>>>(hAb, batch, out);
}